// Round 19
// baseline (5362.554 us; speedup 1.0000x reference)
//
#include <hip/hip_runtime.h>
#include <hip/hip_fp16.h>
#include <math.h>

#define NI 64
#define NO 64
#define NH 512
#define NM 64
#define NN 128
#define NB 32
#define NS 256
#define ZD 2048
#define PD 268
#define NG 128         // GEMM blocks
#define GBLK 160       // 32 batch + 128 GEMM
#define TPB 512
#define ST 580         // LDS stride for inT rows [b][k]
#define RS_ST 68       // padded stride for r tile

// ---- fast transcendentals ----
__device__ __forceinline__ float fexp(float x){ return __expf(x); }
__device__ __forceinline__ float sigm(float x){ return 1.0f/(1.0f+__expf(-x)); }
__device__ __forceinline__ float ftanh(float x){
  float e = __expf(2.f*x);
  return (x > 10.f) ? 1.f : (x < -10.f) ? -1.f : (e - 1.f)/(e + 1.f);
}
__device__ __forceinline__ float softplus_(float x){
  return (x > 15.f) ? x : __logf(1.f + __expf(x));
}
__device__ __forceinline__ float fpow_(float x, float g){   // x>0
  return __expf(g*__logf(x));
}

// ---- packed fp16 dot (v_dot2_f32_f16) with fallback ----
typedef _Float16 h2_t __attribute__((ext_vector_type(2)));
#if defined(__has_builtin)
#if __has_builtin(__builtin_amdgcn_fdot2)
#define HAS_FDOT2 1
#endif
#endif
__device__ __forceinline__ float fdot2_(unsigned int w, unsigned int h, float acc){
#ifdef HAS_FDOT2
  return __builtin_amdgcn_fdot2(__builtin_bit_cast(h2_t, w),
                                __builtin_bit_cast(h2_t, h), acc, false);
#else
  float w0 = __half2float(__builtin_bit_cast(__half, (unsigned short)(w      )));
  float w1 = __half2float(__builtin_bit_cast(__half, (unsigned short)(w >> 16)));
  float h0 = __half2float(__builtin_bit_cast(__half, (unsigned short)(h      )));
  float h1 = __half2float(__builtin_bit_cast(__half, (unsigned short)(h >> 16)));
  return fmaf(w1, h1, fmaf(w0, h0, acc));
#endif
}

// ---- coherent (cross-XCD) access helpers: relaxed system-scope = sc0 sc1 ----
__device__ __forceinline__ float cloadf(const float* p){
  return __hip_atomic_load(p, __ATOMIC_RELAXED, __HIP_MEMORY_SCOPE_SYSTEM);
}
__device__ __forceinline__ void cstoref(float* p, float v){
  __hip_atomic_store(p, v, __ATOMIC_RELAXED, __HIP_MEMORY_SCOPE_SYSTEM);
}
__device__ __forceinline__ float2 cloadf2(const float* p){
  unsigned long long u = __hip_atomic_load((const unsigned long long*)p,
                                           __ATOMIC_RELAXED, __HIP_MEMORY_SCOPE_SYSTEM);
  return __builtin_bit_cast(float2, u);
}
__device__ __forceinline__ unsigned long long cload8(const void* p){
  return __hip_atomic_load((const unsigned long long*)p,
                           __ATOMIC_RELAXED, __HIP_MEMORY_SCOPE_SYSTEM);
}
__device__ __forceinline__ void cstore8(void* p, unsigned long long v){
  __hip_atomic_store((unsigned long long*)p, v,
                     __ATOMIC_RELAXED, __HIP_MEMORY_SCOPE_SYSTEM);
}
__device__ __forceinline__ int cloadi(const int* p){
  return __hip_atomic_load(p, __ATOMIC_RELAXED, __HIP_MEMORY_SCOPE_SYSTEM);
}
__device__ __forceinline__ void cstorei(int* p, int v){
  __hip_atomic_store(p, v, __ATOMIC_RELAXED, __HIP_MEMORY_SCOPE_SYSTEM);
}
__device__ __forceinline__ void caddi(int* p){
  __hip_atomic_fetch_add(p, 1, __ATOMIC_RELAXED, __HIP_MEMORY_SCOPE_SYSTEM);
}
__device__ __forceinline__ void cstoreh(unsigned short* p, unsigned short v){
  __hip_atomic_store(p, v, __ATOMIC_RELAXED, __HIP_MEMORY_SCOPE_SYSTEM);
}

// fp16 pack/unpack
__device__ __forceinline__ unsigned long long packh4(float a, float b, float c, float d){
  unsigned short u0 = __builtin_bit_cast(unsigned short, __float2half(a));
  unsigned short u1 = __builtin_bit_cast(unsigned short, __float2half(b));
  unsigned short u2 = __builtin_bit_cast(unsigned short, __float2half(c));
  unsigned short u3 = __builtin_bit_cast(unsigned short, __float2half(d));
  return (unsigned long long)u0 | ((unsigned long long)u1 << 16)
       | ((unsigned long long)u2 << 32) | ((unsigned long long)u3 << 48);
}
__device__ __forceinline__ void unpackh4(unsigned long long v, float* o){
  o[0] = __half2float(__builtin_bit_cast(__half, (unsigned short)(v      )));
  o[1] = __half2float(__builtin_bit_cast(__half, (unsigned short)(v >> 16)));
  o[2] = __half2float(__builtin_bit_cast(__half, (unsigned short)(v >> 32)));
  o[3] = __half2float(__builtin_bit_cast(__half, (unsigned short)(v >> 48)));
}

// ---- barrier primitives ----
__device__ __forceinline__ void postFlag(int* flags, int idx, int era){
  __syncthreads();                        // payload stores drained (vmcnt0)
  if (threadIdx.x == 0) cstorei(&flags[idx*16], era);
}
__device__ __forceinline__ void postCnt(int* c){
  __syncthreads();                        // payload stores drained (vmcnt0)
  if (threadIdx.x == 0) caddi(c);
}
__device__ __forceinline__ void waitCnt(const int* c, int target){
  if (threadIdx.x == 0) {
    while (cloadi(c) < target) __builtin_amdgcn_s_sleep(2);
  }
  __syncthreads();
}

struct P1S { float inT[8*ST]; float zpart[64*36]; float zfull[512];
             float rs[8*RS_ST]; float hx[16*9]; };
struct P3S { float h[NH]; unsigned long long h16[128]; float pp[544]; float p[PD+4];
             float rk[NM], wk[NM], e[NM], a[NM];
             float sim[NN]; float red[8*64]; float r[NM]; };
union  USH { P1S p1; P3S p3; };

// content+location addressing; 512 threads; mem_s XOR-swizzled:
// logical mem[n][m] at float offset n*64 + (m ^ ((n&7)<<2)).
__device__ void address_head(int t, const float* __restrict__ ks,
                             const float* __restrict__ scal,
                             float* __restrict__ w_arr,
                             const float* __restrict__ mem_s,
                             float* __restrict__ sim_s)
{
  {
    int n = t >> 2, sub = t & 3;
    int cn = (n & 7) << 2;
    float dot = 0.f, sq = 0.f;
#pragma unroll
    for (int i = 0; i < 16; i += 4) {
      int m = sub*16 + i;
      float4 mv = *(const float4*)&mem_s[n*NM + (m ^ cn)];
      float4 kv = *(const float4*)&ks[m];
      dot = fmaf(kv.x, mv.x, dot); dot = fmaf(kv.y, mv.y, dot);
      dot = fmaf(kv.z, mv.z, dot); dot = fmaf(kv.w, mv.w, dot);
      sq  = fmaf(mv.x, mv.x, sq);  sq  = fmaf(mv.y, mv.y, sq);
      sq  = fmaf(mv.z, mv.z, sq);  sq  = fmaf(mv.w, mv.w, sq);
    }
    dot += __shfl_xor(dot, 1); sq += __shfl_xor(sq, 1);
    dot += __shfl_xor(dot, 2); sq += __shfl_xor(sq, 2);
    if (sub == 0) sim_s[n] = dot / (scal[0]*sqrtf(sq) + 1e-8f);
  }
  __syncthreads();
  if (t < 64) {   // wave 0: softmax+gate+shift+sharpen; lane l owns rows l, l+64
    int l = t;
    float beta = scal[1], g = scal[2], s0 = scal[3], s1 = scal[4], s2 = scal[5], gamma = scal[6];
    float x0 = beta*sim_s[l], x1 = beta*sim_s[l+64];
    float mx = fmaxf(x0, x1);
#pragma unroll
    for (int off=32; off; off>>=1) mx = fmaxf(mx, __shfl_xor(mx, off));
    float e0 = fexp(x0-mx), e1 = fexp(x1-mx);
    float sm = e0+e1;
#pragma unroll
    for (int off=32; off; off>>=1) sm += __shfl_xor(sm, off);
    float inv = 1.0f/sm;
    float wg0 = g*e0*inv + (1.f-g)*w_arr[l];
    float wg1 = g*e1*inv + (1.f-g)*w_arr[l+64];
    float up0 = __shfl(wg0, (l+1)&63);
    float w1f = __shfl(wg1, 0);
    float plus0 = (l==63) ? w1f : up0;
    float dn0 = __shfl(wg0, (l-1)&63);
    float w1b = __shfl(wg1, 63);
    float minus0 = (l==0) ? w1b : dn0;
    float up1 = __shfl(wg1, (l+1)&63);
    float w0f = __shfl(wg0, 0);
    float plus1 = (l==63) ? w0f : up1;
    float dn1 = __shfl(wg1, (l-1)&63);
    float w0b = __shfl(wg0, 63);
    float minus1 = (l==0) ? w0b : dn1;
    float ws0 = s0*plus0 + s1*wg0 + s2*minus0;
    float ws1 = s0*plus1 + s1*wg1 + s2*minus1;
    float wp0 = fpow_(fmaxf(ws0, 1e-12f), gamma);
    float wp1 = fpow_(fmaxf(ws1, 1e-12f), gamma);
    float tot = wp0+wp1;
#pragma unroll
    for (int off=32; off; off>>=1) tot += __shfl_xor(tot, off);
    float invt = 1.0f/tot;
    w_arr[l]    = wp0*invt;
    w_arr[l+64] = wp1*invt;
  }
  __syncthreads();
}

extern "C" __global__ __launch_bounds__(TPB, 1)
void ntm_coop(const float* __restrict__ inputs, const float* __restrict__ W_lstm,
              const float* __restrict__ b_lstm, const float* __restrict__ W_int,
              const float* __restrict__ b_int, const float* __restrict__ W_out,
              const float* __restrict__ b_out, float* __restrict__ out,
              float* __restrict__ wsf)
{
  __shared__ float mem_s[NN*NM];          // 32 KB persistent memory (batch blocks)
  __shared__ float wr_s[NN], ww_s[NN];
  __shared__ float scal_s[14];
  __shared__ USH u;

  int*    cbase   = (int*)wsf;            // cnt_g[q] @ [q*16] (q<8: 4 groups x 2); cnt_w @ [256]
  int*    flags_r = (int*)wsf + 1024;     // 32 lines: r(s) posted (era s+1)
  __half* hT16    = (__half*)(wsf + 8192);   // [par][batch][unit] fp16: 2*512*32 halves
  float*  rT      = wsf + 8192 + 16384;   // [batch][m] 32*64
  float*  WrT     = rT + NB*NM;           // [col][k] fp32 2048*64
  unsigned short* WintT16 = (unsigned short*)(WrT + ZD*64);  // [c][k] 268*512 fp16
  unsigned short* WoutT16 = WintT16 + PD*NH;                 // [c][k] 64*576 fp16

  const int t   = threadIdx.x;
  const int bid = blockIdx.x;
  const bool isB = (bid < NB);

  // ---- one-time weight transposes/converts (coherent stores; cnt_w barrier) ----
  {
    int gid = bid*TPB + t;
    for (int idx = gid; idx < PD*NH; idx += GBLK*TPB) {
      int c = idx >> 9, k = idx & 511;
      cstoreh(&WintT16[idx],
              __builtin_bit_cast(unsigned short, __float2half(W_int[(size_t)k*PD + c])));
    }
    for (int idx = gid; idx < NO*576; idx += GBLK*TPB) {
      int c = idx / 576, k = idx - c*576;
      cstoreh(&WoutT16[idx],
              __builtin_bit_cast(unsigned short, __float2half(W_out[(size_t)k*NO + c])));
    }
    for (int idx = gid; idx < ZD*64; idx += GBLK*TPB) {
      int c = idx >> 6, k = idx & 63;
      cstoref(&WrT[idx], W_lstm[(size_t)(64 + k)*ZD + c]);
    }
  }
  postCnt(&cbase[256]);                   // one-time: converts drained
  waitCnt(&cbase[256], GBLK);             // one-time: all converts visible

  if (!isB) {
    // ==== GEMM role: 4 independent groups of 32 blocks; 8 batches/group ====
    const int gb   = bid - NB;             // 0..127
    const int bg   = gb >> 5;              // group 0..3
    const int gbl  = gb & 31;              // block in group
    const int b0   = bg * 8;               // first batch of group
    const int j0   = ((gbl & 7) << 6) + ((gbl >> 3) << 4);  // 16 units, XCD-contig
    // z decode: (kp, col-quad, batch)
    const int kp   = t >> 7;               // 0..3
    const int rem  = t & 127;
    const int c4   = rem >> 3;             // 0..15
    const int pb8  = rem & 7;              // batch in group
    const int gate4= c4 >> 2;
    const int u4   = (c4 & 3) * 4;
    const int colg = gate4*NH + j0 + u4;
    // pointwise decode (t<128)
    const int pj   = t >> 3;               // unit-local 0..15
    const int pw8  = t & 7;                // batch in group
    const int cntq = bg*2 + (gbl >> 4);    // this block's post counter
    float c_reg = 0.f;
    __syncthreads();

    for (int step = 0; step < NS; ++step) {
      const __half* h16_prev = hT16 + (size_t)((step & 1) ^ 1)*NH*NB;
      __half*       h16_cur  = hT16 + (size_t)(step & 1)*NH*NB;

      // ---- stage x(s) (independent of h; before the wait) ----
      if (t < 128) {
        int sb = t >> 4, k4 = (t & 15) * 4;
        float4 xv = *(const float4*)(inputs + ((size_t)(b0+sb)*NS + step)*NI + k4);
        *(float4*)&u.p1.inT[sb*ST + k4] = xv;
      }

      // ---- own group's h(s-1) visible: 2 counters ----
      if (step) {
        if (t < 2) {
          const int tgt = 16*step;
          while (cloadi(&cbase[(bg*2 + t)*16]) < tgt) __builtin_amdgcn_s_sleep(1);
        }
        __syncthreads();
      }

      // ---- stage h(s-1): 8 batches x 512 units fp16 = 1024 ull ----
      if (step == 0) {
#pragma unroll
        for (int i = 0; i < 2; ++i) {
          int q = t + 512*i; int b_ = q >> 7, u_ = (q & 127) * 4;
          *(float4*)&u.p1.inT[b_*ST + 64 + u_] = make_float4(0.f,0.f,0.f,0.f);
        }
      } else {
#pragma unroll
        for (int i = 0; i < 2; ++i) {
          int q = t + 512*i; int b_ = q >> 7, u_ = (q & 127) * 4;
          unsigned long long v = cload8(h16_prev + (size_t)(b0+b_)*NH + u_);
          float o[4]; unpackh4(v, o);
          *(float4*)&u.p1.inT[b_*ST + 64 + u_] = make_float4(o[0],o[1],o[2],o[3]);
        }
      }
      __syncthreads();

      // ---- z_xh(s): 64 cols x 8 batches; per thread 4 cols x k-slice ----
      float a0=0.f, a1=0.f, a2=0.f, a3=0.f;
      {
        const float* xr = &u.p1.inT[pb8*ST + kp*16];
        const float* Wp = W_lstm + (size_t)(kp*16)*ZD + colg;
#pragma unroll
        for (int k4 = 0; k4 < 16; k4 += 4) {
          float4 x = *(const float4*)&xr[k4];
          float4 w0 = *(const float4*)(Wp + (size_t)(k4+0)*ZD);
          float4 w1 = *(const float4*)(Wp + (size_t)(k4+1)*ZD);
          float4 w2 = *(const float4*)(Wp + (size_t)(k4+2)*ZD);
          float4 w3 = *(const float4*)(Wp + (size_t)(k4+3)*ZD);
          a0 = fmaf(x.x, w0.x, a0); a1 = fmaf(x.x, w0.y, a1);
          a2 = fmaf(x.x, w0.z, a2); a3 = fmaf(x.x, w0.w, a3);
          a0 = fmaf(x.y, w1.x, a0); a1 = fmaf(x.y, w1.y, a1);
          a2 = fmaf(x.y, w1.z, a2); a3 = fmaf(x.y, w1.w, a3);
          a0 = fmaf(x.z, w2.x, a0); a1 = fmaf(x.z, w2.y, a1);
          a2 = fmaf(x.z, w2.z, a2); a3 = fmaf(x.z, w2.w, a3);
          a0 = fmaf(x.w, w3.x, a0); a1 = fmaf(x.w, w3.y, a1);
          a2 = fmaf(x.w, w3.z, a2); a3 = fmaf(x.w, w3.w, a3);
        }
        const float* hr = &u.p1.inT[pb8*ST + 64 + kp*128];
        const float* Wh = W_lstm + (size_t)(128 + kp*128)*ZD + colg;
#pragma unroll 4
        for (int k4 = 0; k4 < 128; k4 += 4) {
          float4 x = *(const float4*)&hr[k4];
          float4 w0 = *(const float4*)(Wh + (size_t)(k4+0)*ZD);
          float4 w1 = *(const float4*)(Wh + (size_t)(k4+1)*ZD);
          float4 w2 = *(const float4*)(Wh + (size_t)(k4+2)*ZD);
          float4 w3 = *(const float4*)(Wh + (size_t)(k4+3)*ZD);
          a0 = fmaf(x.x, w0.x, a0); a1 = fmaf(x.x, w0.y, a1);
          a2 = fmaf(x.x, w0.z, a2); a3 = fmaf(x.x, w0.w, a3);
          a0 = fmaf(x.y, w1.x, a0); a1 = fmaf(x.y, w1.y, a1);
          a2 = fmaf(x.y, w1.z, a2); a3 = fmaf(x.y, w1.w, a3);
          a0 = fmaf(x.z, w2.x, a0); a1 = fmaf(x.z, w2.y, a1);
          a2 = fmaf(x.z, w2.z, a2); a3 = fmaf(x.z, w2.w, a3);
          a0 = fmaf(x.w, w3.x, a0); a1 = fmaf(x.w, w3.y, a1);
          a2 = fmaf(x.w, w3.z, a2); a3 = fmaf(x.w, w3.w, a3);
        }
        if (step == 0) {   // bake z_r(0) from r_init = 0.01 (rows 64..127)
          const float* Wr0 = W_lstm + (size_t)(64 + kp*16)*ZD + colg;
#pragma unroll
          for (int k = 0; k < 16; ++k) {
            float4 w = *(const float4*)(Wr0 + (size_t)k*ZD);
            a0 = fmaf(0.01f, w.x, a0); a1 = fmaf(0.01f, w.y, a1);
            a2 = fmaf(0.01f, w.z, a2); a3 = fmaf(0.01f, w.w, a3);
          }
        }
      }
      { int base = (kp*16 + c4)*36 + pb8;   // padded stride 36, ci stride 9
        u.p1.zpart[base]      = a0;
        u.p1.zpart[base + 9]  = a1;
        u.p1.zpart[base + 18] = a2;
        u.p1.zpart[base + 27] = a3; }

      // ---- wait r(s-1) for own 8 batches; stage to LDS ----
      if (step) {
        if (t < 8) {
          while (cloadi(&flags_r[(b0 + t)*16]) < step) __builtin_amdgcn_s_sleep(1);
        }
        __syncthreads();
        if (t < 256) {
          int bb = t >> 5, kk = (t & 31) * 2;
          float2 v = cloadf2(rT + (size_t)(b0+bb)*64 + kk);
          *(float2*)&u.p1.rs[bb*RS_ST + kk] = v;
        }
      }
      __syncthreads();

      // ---- reduce z across kp: col = t>>3 (0..63), pb = t&7 ----
      {
        int col = t >> 3, pb = t & 7;
        int c4r = col >> 2, cir = col & 3;
        float z = u.p1.zpart[(c4r)*36 + cir*9 + pb]
                + u.p1.zpart[(16 + c4r)*36 + cir*9 + pb]
                + u.p1.zpart[(32 + c4r)*36 + cir*9 + pb]
                + u.p1.zpart[(48 + c4r)*36 + cir*9 + pb]
                + b_lstm[(col >> 4)*NH + j0 + (col & 15)];
        u.p1.zfull[t] = z;                 // zfull[col*8 + pb] == zfull[t]
      }
      __syncthreads();

      // ---- pointwise: z = z_xh + z_r + bias -> c,h (t<128: 16 units x 8 batches) ----
      if (t < 128) {
        float zrv[4] = {0.f, 0.f, 0.f, 0.f};
        if (step) {
          const float* rr = &u.p1.rs[pw8*RS_ST];
#pragma unroll
          for (int gt = 0; gt < 4; ++gt) {
            const float* Wc = WrT + (size_t)(gt*NH + j0 + pj)*64;
            float acc = 0.f;
#pragma unroll
            for (int k = 0; k < 64; k += 4) {
              float4 w = *(const float4*)&Wc[k];
              acc = fmaf(rr[k],   w.x, acc);
              acc = fmaf(rr[k+1], w.y, acc);
              acc = fmaf(rr[k+2], w.z, acc);
              acc = fmaf(rr[k+3], w.w, acc);
            }
            zrv[gt] = acc;
          }
        }
        float zv[4];
#pragma unroll
        for (int gt = 0; gt < 4; ++gt)
          zv[gt] = u.p1.zfull[(gt*16 + pj)*8 + pw8] + zrv[gt];
        float cn = sigm(zv[1])*c_reg + sigm(zv[0])*ftanh(zv[2]);
        c_reg = cn;
        u.p1.hx[pj*9 + pw8] = sigm(zv[3])*ftanh(cn);
      }
      __syncthreads();
      if (t < 32) {   // pack 4 units -> one 8B fp16 store; 4 stores per batch row
        int b8 = t >> 2, q4 = t & 3;
        unsigned long long v = packh4(u.p1.hx[(q4*4+0)*9 + b8],
                                      u.p1.hx[(q4*4+1)*9 + b8],
                                      u.p1.hx[(q4*4+2)*9 + b8],
                                      u.p1.hx[(q4*4+3)*9 + b8]);
        cstore8(h16_cur + (size_t)(b0+b8)*NH + j0 + q4*4, v);
      }
      postCnt(&cbase[cntq*16]);            // h slice posted -> group counter
    }
  } else {
    // ==================== batch role (32 blocks) ====================
    const int b = bid;
    const int g = b >> 3;                  // group
    for (int i = t; i < NN*NM; i += TPB) mem_s[i] = 0.01f;
    if (t < NN) { wr_s[t] = (t==0)?1.f:0.f; ww_s[t] = (t==0)?1.f:0.f; }
    __syncthreads();

    for (int step = 0; step < NS; ++step) {
      const int era = step + 1;
      const __half* h16_cur = hT16 + (size_t)(step & 1)*NH*NB;

      // ---- wait own group's h(s): 2 counters ----
      if (t < 2) {
        const int tgt = 16*era;
        while (cloadi(&cbase[(g*2 + t)*16]) < tgt) __builtin_amdgcn_s_sleep(1);
      }
      __syncthreads();

      // ---- read own h row (coalesced coherent, 1 KB): raw fp16 + floats ----
      if (t < 128) {
        unsigned long long v = cload8(h16_cur + (size_t)b*NH + 4*t);
        u.p3.h16[t] = v;
        float o[4]; unpackh4(v, o);
        *(float4*)&u.p3.h[4*t] = make_float4(o[0],o[1],o[2],o[3]);
      }
      __syncthreads();

      // ---- p = h @ W_int + b_int (packed fp16 dot2; weights XCD-L2 resident) ----
      {
        int c = t >> 1, kh = t & 1;
        const unsigned long long* Wc =
            (const unsigned long long*)(WintT16 + (size_t)c*512 + kh*256);
        const unsigned long long* hh = u.p3.h16 + kh*64;   // 256 halves = 64 ull
        float pacc = 0.f;
#pragma unroll 8
        for (int k = 0; k < 64; ++k) {
          unsigned long long w = Wc[k], hv = hh[k];
          pacc = fdot2_((unsigned int)w,        (unsigned int)hv,        pacc);
          pacc = fdot2_((unsigned int)(w >> 32),(unsigned int)(hv >> 32), pacc);
        }
        u.p3.pp[t] = pacc;
        if (t < 24) {
          int id = 512 + t; int c2 = id >> 1; int k2 = id & 1;
          const unsigned long long* Wc2 =
              (const unsigned long long*)(WintT16 + (size_t)c2*512 + k2*256);
          const unsigned long long* hh2 = u.p3.h16 + k2*64;
          float pa2 = 0.f;
#pragma unroll 8
          for (int k = 0; k < 64; ++k) {
            unsigned long long w = Wc2[k], hv = hh2[k];
            pa2 = fdot2_((unsigned int)w,        (unsigned int)hv,        pa2);
            pa2 = fdot2_((unsigned int)(w >> 32),(unsigned int)(hv >> 32), pa2);
          }
          u.p3.pp[id] = pa2;
        }
      }
      __syncthreads();
      if (t < PD) u.p3.p[t] = u.p3.pp[2*t] + u.p3.pp[2*t+1] + b_int[t];
      __syncthreads();

      // head params
      if (t < NM) {
        float rk = ftanh(u.p3.p[t]);
        float wk = ftanh(u.p3.p[70+t]);
        u.p3.rk[t] = rk; u.p3.wk[t] = wk;
        u.p3.e[t] = sigm(u.p3.p[140+t]);
        u.p3.a[t] = ftanh(u.p3.p[204+t]);
        float sr = rk*rk, sw = wk*wk;
#pragma unroll
        for (int off=32; off; off>>=1){ sr += __shfl_xor(sr,off); sw += __shfl_xor(sw,off); }
        if (t == 0) { scal_s[0] = sqrtf(sr); scal_s[7] = sqrtf(sw); }
      }
      if (t == 64) {
        scal_s[1] = softplus_(u.p3.p[64]);
        scal_s[2] = sigm(u.p3.p[65]);
        float a0=u.p3.p[66], a1=u.p3.p[67], a2=u.p3.p[68];
        float m = fmaxf(a0,fmaxf(a1,a2));
        float e0=fexp(a0-m), e1=fexp(a1-m), e2=fexp(a2-m);
        float s = e0+e1+e2;
        scal_s[3]=e0/s; scal_s[4]=e1/s; scal_s[5]=e2/s;
        scal_s[6] = 1.f + softplus_(u.p3.p[69]);
      }
      if (t == 128) {
        scal_s[8]  = softplus_(u.p3.p[134]);
        scal_s[9]  = sigm(u.p3.p[135]);
        float a0=u.p3.p[136], a1=u.p3.p[137], a2=u.p3.p[138];
        float m = fmaxf(a0,fmaxf(a1,a2));
        float e0=fexp(a0-m), e1=fexp(a1-m), e2=fexp(a2-m);
        float s = e0+e1+e2;
        scal_s[10]=e0/s; scal_s[11]=e1/s; scal_s[12]=e2/s;
        scal_s[13] = 1.f + softplus_(u.p3.p[139]);
      }
      __syncthreads();

      address_head(t, u.p3.wk, &scal_s[7], ww_s, mem_s, u.p3.sim);

      {  // erase + add
        int n = t >> 2, sub = t & 3;
        int cn = (n & 7) << 2;
        float w = ww_s[n];
#pragma unroll
        for (int i = 0; i < 16; i += 4) {
          int m = sub*16 + i;
          float* mp = &mem_s[n*NM + (m ^ cn)];
          float4 mv = *(float4*)mp;
          float4 ev = *(const float4*)&u.p3.e[m];
          float4 av = *(const float4*)&u.p3.a[m];
          mv.x = mv.x*(1.f - w*ev.x) + w*av.x;
          mv.y = mv.y*(1.f - w*ev.y) + w*av.y;
          mv.z = mv.z*(1.f - w*ev.z) + w*av.z;
          mv.w = mv.w*(1.f - w*ev.w) + w*av.w;
          *(float4*)mp = mv;
        }
      }
      __syncthreads();

      address_head(t, u.p3.rk, &scal_s[0], wr_s, mem_s, u.p3.sim);

      {  // r = w_r @ mem
        int part = t >> 6, m = t & 63;
        float racc = 0.f;
#pragma unroll
        for (int nn = 0; nn < 16; ++nn) {
          int n = part*16 + nn;
          racc = fmaf(wr_s[n], mem_s[n*NM + (m ^ ((n&7)<<2))], racc);
        }
        u.p3.red[part*64 + m] = racc;
      }
      __syncthreads();
      if (t < NM) {
        float rv = 0.f;
#pragma unroll
        for (int pq = 0; pq < 8; ++pq) rv += u.p3.red[pq*64 + t];
        u.p3.r[t] = rv;
        cstoref(&rT[b*NM + t], rv);
      }
      postFlag(flags_r, b, era);          // r(s) visible -> group's GEMM proceeds

      // ---- off-path: out(s) = [h, r] @ W_out + b_out (fp16 weights) ----
      {
        int part = t >> 6, c = t & 63;
        const unsigned long long* Wc =
            (const unsigned long long*)(WoutT16 + (size_t)c*576 + part*72);
        float oacc = 0.f;
        int k0 = part*72;
#pragma unroll
        for (int kk = 0; kk < 72; kk += 4) {
          float o[4]; unpackh4(Wc[kk >> 2], o);
          int k = k0 + kk;
          float v0 = (k   < NH) ? u.p3.h[k]   : u.p3.r[k-NH];
          float v1 = (k+1 < NH) ? u.p3.h[k+1] : u.p3.r[k+1-NH];
          float v2 = (k+2 < NH) ? u.p3.h[k+2] : u.p3.r[k+2-NH];
          float v3 = (k+3 < NH) ? u.p3.h[k+3] : u.p3.r[k+3-NH];
          oacc = fmaf(v0, o[0], oacc);
          oacc = fmaf(v1, o[1], oacc);
          oacc = fmaf(v2, o[2], oacc);
          oacc = fmaf(v3, o[3], oacc);
        }
        u.p3.red[part*64 + c] = oacc;
      }
      __syncthreads();
      if (t < NO) {
        float ov = b_out[t];
#pragma unroll
        for (int pq = 0; pq < 8; ++pq) ov += u.p3.red[pq*64 + t];
        out[(size_t)b*NS*NO + (size_t)step*NO + t] = ov;
      }
      __syncthreads();
    }
  }
}

extern "C" void kernel_launch(void* const* d_in, const int* in_sizes, int n_in,
                              void* d_out, int out_size, void* d_ws, size_t ws_size,
                              hipStream_t stream) {
  const float* inputs = (const float*)d_in[0];
  const float* W_lstm = (const float*)d_in[1];
  const float* b_lstm = (const float*)d_in[2];
  const float* W_int  = (const float*)d_in[3];
  const float* b_int  = (const float*)d_in[4];
  const float* W_out  = (const float*)d_in[5];
  const float* b_out  = (const float*)d_in[6];
  float* outp = (float*)d_out;
  float* wsp  = (float*)d_ws;

  hipMemsetAsync(d_ws, 0, 32768, stream);   // zero cnt_g/cnt_w/flags_r each launch

  void* args[] = { (void*)&inputs, (void*)&W_lstm, (void*)&b_lstm,
                   (void*)&W_int, (void*)&b_int, (void*)&W_out, (void*)&b_out,
                   (void*)&outp, (void*)&wsp };
  hipLaunchCooperativeKernel((const void*)ntm_coop, dim3(GBLK), dim3(TPB),
                             args, 0, stream);
}